// Round 1
// baseline (3649.277 us; speedup 1.0000x reference)
//
#include <hip/hip_runtime.h>

#define B_SZ 8192
#define T_SZ 12
#define N_SZ 8
#define FIN  16
#define U_SZ 64
#define R_WG 32
#define NTHR 256

__device__ __forceinline__ float sigm(float x){ return 1.f/(1.f + __expf(-x)); }
__device__ __forceinline__ float tanh_f(float x){
  float ax = fabsf(x);
  float e = __expf(-2.f*ax);
  float t = (1.f - e)/(1.f + e);
  return x < 0.f ? -t : t;
}

__device__ __forceinline__ void stage_lds(float* dst, const float* src, int n, int tid){
  for (int i = tid; i < n; i += NTHR) dst[i] = src[i];
}

// out[r*64+u] = act( (addend? addend[r*64+u]:0) + (bias? bias[u]:0) + sum_{k<64} x[r*xstride+k]*w[k*64+u] )
__device__ __forceinline__ void small_gemm(float* out, const float* x, int xstride,
                                           const float* w, const float* bias,
                                           const float* addend, bool relu, int tid){
  int u = tid & 63, rg = tid >> 6;
  float acc[8];
  #pragma unroll
  for (int ri = 0; ri < 8; ri++) acc[ri] = 0.f;
  for (int k4 = 0; k4 < 64; k4 += 4){
    float w0 = w[(k4+0)*64+u], w1 = w[(k4+1)*64+u];
    float w2 = w[(k4+2)*64+u], w3 = w[(k4+3)*64+u];
    #pragma unroll
    for (int ri = 0; ri < 8; ri++){
      const float4 xv = *(const float4*)(x + (rg*8+ri)*xstride + k4);
      acc[ri] += xv.x*w0 + xv.y*w1 + xv.z*w2 + xv.w*w3;
    }
  }
  float b = bias ? bias[u] : 0.f;
  #pragma unroll
  for (int ri = 0; ri < 8; ri++){
    int r = rg*8+ri;
    float v = acc[ri] + b;
    if (addend) v += addend[r*64+u];
    if (relu) v = fmaxf(v, 0.f);
    out[r*64+u] = v;
  }
}

// acc[half][ri*4+g] = sum_{k<80} x80[(rg*4+ri)*80+k] * W[half][k][ul][g]   (u = half*32+ul)
__device__ __forceinline__ void lstm_gemm(float acc[2][16], const float* Wsrc, float* wbuf,
                                          const float* x80, int tid){
  int ul = tid & 31, rg = tid >> 5;
  #pragma unroll
  for (int half = 0; half < 2; half++){
    __syncthreads();
    stage_lds(wbuf, Wsrc + half*10240, 10240, tid);
    __syncthreads();
    float a[16];
    #pragma unroll
    for (int i = 0; i < 16; i++) a[i] = 0.f;
    for (int k4 = 0; k4 < 80; k4 += 4){
      float4 wv0 = *(const float4*)(wbuf + (k4+0)*128 + ul*4);
      float4 wv1 = *(const float4*)(wbuf + (k4+1)*128 + ul*4);
      float4 wv2 = *(const float4*)(wbuf + (k4+2)*128 + ul*4);
      float4 wv3 = *(const float4*)(wbuf + (k4+3)*128 + ul*4);
      #pragma unroll
      for (int ri = 0; ri < 4; ri++){
        const float4 xv = *(const float4*)(x80 + (rg*4+ri)*80 + k4);
        a[ri*4+0] += xv.x*wv0.x + xv.y*wv1.x + xv.z*wv2.x + xv.w*wv3.x;
        a[ri*4+1] += xv.x*wv0.y + xv.y*wv1.y + xv.z*wv2.y + xv.w*wv3.y;
        a[ri*4+2] += xv.x*wv0.z + xv.y*wv1.z + xv.z*wv2.z + xv.w*wv3.z;
        a[ri*4+3] += xv.x*wv0.w + xv.y*wv1.w + xv.z*wv2.w + xv.w*wv3.w;
      }
    }
    #pragma unroll
    for (int i = 0; i < 16; i++) acc[half][i] = a[i];
  }
  __syncthreads();
}

__device__ __forceinline__ void lstm_nonlin(const float acc[2][16], const float* b4,
                                            float* cg, int cstride, float* hout, int tid){
  int ul = tid & 31, rg = tid >> 5;
  #pragma unroll
  for (int half = 0; half < 2; half++){
    int u = ul + 32*half;
    float bi = b4[u*4+0], bf = b4[u*4+1], bg = b4[u*4+2], bo = b4[u*4+3];
    #pragma unroll
    for (int ri = 0; ri < 4; ri++){
      int r = rg*4+ri;
      float iv = sigm(acc[half][ri*4+0] + bi);
      float fv = sigm(acc[half][ri*4+1] + bf);
      float gv = tanh_f(acc[half][ri*4+2] + bg);
      float ov = sigm(acc[half][ri*4+3] + bo);
      float c  = cg[r*cstride + u];
      float c2 = fv*c + iv*gv;
      cg[r*cstride + u] = c2;
      hout[r*64+u] = ov * tanh_f(c2);
    }
  }
}

struct StepPtrs {
  const float* ts; const float* gts;
  const float* W4ts; const float* b4ts;
  const float* W4nd; const float* b4nd;
  const float* Qt; const float* Kw; const float* Vt; const float* Ft;
  const float* F1a; const float* F1b;
  const float* Qb; const float* Vb; const float* Fb; const float* f1b;
  float* h_node; float* c_node; float* h_tsa_g; float* c_ts;
};

__global__ __launch_bounds__(NTHR) void step_kernel(StepPtrs P, int t){
  __shared__ __align__(16) float h_node[R_WG*8*64];   // 16384
  __shared__ __align__(16) float x80[R_WG*80];        // 2560 ; tempH aliases first 2048
  __shared__ __align__(16) float h_ts [R_WG*64];
  __shared__ __align__(16) float h_tsa[R_WG*64];
  __shared__ __align__(16) float tmpA [R_WG*64];
  __shared__ __align__(16) float tmpB [R_WG*64];
  __shared__ __align__(16) float wbuf[10240];         // 40KB weight scratch
  __shared__ float b4[256];
  __shared__ float pbuf[256];
  float* tempH = x80;

  const int tid = threadIdx.x;
  const int r0  = blockIdx.x * R_WG;
  float acc[2][16];

  // load persistent states
  stage_lds(h_node, P.h_node + (size_t)r0*512, R_WG*512, tid);
  stage_lds(h_tsa,  P.h_tsa_g + (size_t)r0*64, R_WG*64, tid);

  // ---------------- ts LSTM ----------------
  for (int i = tid; i < R_WG*FIN; i += NTHR){
    int r = i >> 4, m = i & 15;
    x80[r*80 + m] = P.ts[(size_t)(r0+r)*(T_SZ*FIN) + t*FIN + m];
  }
  for (int i = tid; i < R_WG*64; i += NTHR){   // same-thread as h_tsa staging (stride NTHR)
    int r = i >> 6, c = i & 63;
    x80[r*80 + 16 + c] = h_tsa[i];
  }
  stage_lds(b4, P.b4ts + t*256, 256, tid);
  lstm_gemm(acc, P.W4ts + t*20480, wbuf, x80, tid);
  lstm_nonlin(acc, b4, P.c_ts + (size_t)r0*64, 64, h_ts, tid);

  // ---------------- node LSTMs ----------------
  for (int n = 0; n < N_SZ; n++){
    __syncthreads();
    for (int i = tid; i < R_WG*FIN; i += NTHR){
      int r = i >> 4, m = i & 15;
      x80[r*80 + m] = P.gts[((size_t)(r0+r)*N_SZ + n)*(T_SZ*FIN) + t*FIN + m];
    }
    for (int i = tid; i < R_WG*64; i += NTHR){
      int r = i >> 6, c = i & 63;
      x80[r*80 + 16 + c] = h_node[(r*8+n)*64 + c];
    }
    stage_lds(b4, P.b4nd + (n*T_SZ + t)*256, 256, tid);
    lstm_gemm(acc, P.W4nd + (size_t)(n*T_SZ + t)*20480, wbuf, x80, tid);
    lstm_nonlin(acc, b4, P.c_node + ((size_t)r0*8 + n)*64, 512, tempH, tid);
    __syncthreads();
    for (int i = tid; i < R_WG*64; i += NTHR){
      int r = i >> 6, c = i & 63;
      h_node[(r*8+n)*64 + c] = tempH[i];
    }
  }
  __syncthreads();

  // ---------------- attention ----------------
  stage_lds(wbuf, P.Qt, 4096, tid); __syncthreads();
  small_gemm(tmpA, h_ts, 64, wbuf, P.Qb, nullptr, false, tid);   // q
  __syncthreads();
  stage_lds(wbuf, P.Kw, 4096, tid); __syncthreads();
  small_gemm(tmpB, tmpA, 64, wbuf, nullptr, nullptr, false, tid); // qk = q @ Kw
  __syncthreads();
  { // scores + softmax (lane-rotated reads: conflict-free)
    int r = tid >> 3, n = tid & 7, lane = tid & 63;
    float s = 0.f;
    for (int c0 = 0; c0 < 64; c0++){
      int c = (c0 + lane) & 63;
      s += h_node[(r*8+n)*64 + c] * tmpB[r*64 + c];
    }
    s *= 0.125f;                       // 1/sqrt(U)
    float mx = s;
    mx = fmaxf(mx, __shfl_xor(mx, 1, 8));
    mx = fmaxf(mx, __shfl_xor(mx, 2, 8));
    mx = fmaxf(mx, __shfl_xor(mx, 4, 8));
    float e = __expf(s - mx);
    float sum = e;
    sum += __shfl_xor(sum, 1, 8);
    sum += __shfl_xor(sum, 2, 8);
    sum += __shfl_xor(sum, 4, 8);
    pbuf[tid] = e / sum;
  }
  __syncthreads();
  { // hbar = sum_n p_n * h_g[n]  -> tmpA (q dead)
    int u = tid & 63, rg = tid >> 6;
    #pragma unroll
    for (int ri = 0; ri < 8; ri++){
      int r = rg*8+ri;
      float a = 0.f;
      #pragma unroll
      for (int n = 0; n < 8; n++) a += pbuf[r*8+n] * h_node[(r*8+n)*64 + u];
      tmpA[r*64+u] = a;
    }
  }
  __syncthreads();
  stage_lds(wbuf, P.Vt, 4096, tid); __syncthreads();
  small_gemm(tmpB, tmpA, 64, wbuf, P.Vb, nullptr, false, tid);    // ctx
  __syncthreads();
  stage_lds(wbuf, P.Ft, 8192, tid); __syncthreads();
  small_gemm(h_tsa, tmpB, 64, wbuf, P.Fb, nullptr, false, tid);         // ctx part
  small_gemm(h_tsa, h_ts, 64, wbuf + 4096, nullptr, h_tsa, true, tid);  // + query part, relu
  __syncthreads();

  // ---------------- fusion ----------------
  stage_lds(wbuf, P.F1b, 4096, tid); __syncthreads();
  small_gemm(tmpA, h_ts, 64, wbuf, P.f1b, nullptr, false, tid);   // f_ts
  __syncthreads();
  stage_lds(wbuf, P.F1a, 4096, tid); __syncthreads();
  for (int n = 0; n < N_SZ; n++){
    small_gemm(tempH, h_node + n*64, 512, wbuf, nullptr, tmpA, true, tid);
    __syncthreads();
    for (int i = tid; i < R_WG*64; i += NTHR){
      int r = i >> 6, c = i & 63;
      h_node[(r*8+n)*64 + c] = tempH[i];
    }
    __syncthreads();
  }

  // ---------------- writeback ----------------
  for (int i = tid; i < R_WG*512; i += NTHR) P.h_node[(size_t)r0*512 + i] = h_node[i];
  for (int i = tid; i < R_WG*64;  i += NTHR) P.h_tsa_g[(size_t)r0*64 + i] = h_tsa[i];
}

// ---- prep kernels: fold embedding into Wih, gate-interleave, transpose att/fuse weights ----
__global__ void prep_w_kernel(const float* Wih, const float* Whh, const float* emb_w,
                              float* dst, int L){
  int idx = blockIdx.x*256 + threadIdx.x;
  int total = L*80*64;
  if (idx >= total) return;
  int l = idx / (80*64);
  int rem = idx % (80*64);
  int k = rem / 64;
  int u = rem & 63;
  int half = u >> 5, ul = u & 31;
  float v[4];
  if (k < FIN){
    #pragma unroll
    for (int g = 0; g < 4; g++){
      int j = g*64 + u;
      float s = 0.f;
      for (int i = 0; i < 32; i++) s += Wih[((size_t)l*256 + j)*32 + i] * emb_w[i*16 + k];
      v[g] = s;
    }
  } else {
    #pragma unroll
    for (int g = 0; g < 4; g++) v[g] = Whh[((size_t)l*256 + g*64+u)*64 + (k-FIN)];
  }
  float* d = dst + (size_t)l*20480 + (half*80 + k)*128 + ul*4;
  d[0]=v[0]; d[1]=v[1]; d[2]=v[2]; d[3]=v[3];
}

__global__ void prep_b_kernel(const float* bih, const float* bhh, const float* Wih,
                              const float* emb_b, float* dst, int L){
  int idx = blockIdx.x*256 + threadIdx.x;
  if (idx >= L*64) return;
  int l = idx / 64, u = idx & 63;
  #pragma unroll
  for (int g = 0; g < 4; g++){
    int j = g*64+u;
    float s = bih[l*256+j] + bhh[l*256+j];
    for (int i = 0; i < 32; i++) s += Wih[((size_t)l*256+j)*32+i] * emb_b[i];
    dst[l*256 + u*4 + g] = s;
  }
}

__global__ void prep_att_kernel(const float* Qw, const float* Vw, const float* Fw, const float* f1w,
                                float* Qt, float* Vt, float* Ft, float* F1a, float* F1b){
  int idx = blockIdx.x*256 + threadIdx.x;
  if (idx < 4096){
    int c = idx >> 6, u = idx & 63;
    Qt[c*64+u]  = Qw[u*64+c];
    Vt[c*64+u]  = Vw[u*64+c];
    F1a[c*64+u] = f1w[u*128 + c];
    F1b[c*64+u] = f1w[u*128 + 64 + c];
  }
  if (idx < 8192){
    int m = idx >> 6, j = idx & 63;
    Ft[m*64+j] = Fw[j*128 + m];
  }
}

__global__ __launch_bounds__(256) void final_kernel(const float* h_tsa_g, const float* w1,
                                                    const float* b1, const float* w2,
                                                    const float* b2, float* out){
  __shared__ __align__(16) float xs[64*64];
  __shared__ float w1s[2048];
  __shared__ float b1s[32], w2s[32];
  int tid = threadIdx.x;
  int r0 = blockIdx.x * 64;
  for (int i = tid; i < 4096; i += 256) xs[i] = h_tsa_g[(size_t)r0*64 + i];
  for (int i = tid; i < 2048; i += 256) w1s[i] = w1[i];
  if (tid < 32){ b1s[tid] = b1[tid]; w2s[tid] = w2[tid]; }
  __syncthreads();
  int r = tid >> 2, q = tid & 3;
  float p = 0.f;
  #pragma unroll
  for (int ii = 0; ii < 8; ii++){
    int i = q*8 + ii;
    float h = b1s[i];
    for (int u4 = 0; u4 < 64; u4 += 4){
      const float4 xv = *(const float4*)(xs + r*64 + u4);
      h += xv.x*w1s[i*64+u4] + xv.y*w1s[i*64+u4+1] + xv.z*w1s[i*64+u4+2] + xv.w*w1s[i*64+u4+3];
    }
    p += w2s[i] * fmaxf(h, 0.f);
  }
  p += __shfl_xor(p, 1, 4);
  p += __shfl_xor(p, 2, 4);
  if (q == 0) out[r0 + r] = p + b2[0];
}

extern "C" void kernel_launch(void* const* d_in, const int* in_sizes, int n_in,
                              void* d_out, int out_size, void* d_ws, size_t ws_size,
                              hipStream_t stream){
  const float* ts      = (const float*)d_in[0];
  const float* gts     = (const float*)d_in[1];
  const float* emb_w   = (const float*)d_in[2];
  const float* emb_b   = (const float*)d_in[3];
  const float* attQ_w  = (const float*)d_in[4];
  const float* attQ_b  = (const float*)d_in[5];
  const float* attK_w  = (const float*)d_in[6];
  // d_in[7] = attK_b : unused (constant shift under softmax)
  const float* attV_w  = (const float*)d_in[8];
  const float* attV_b  = (const float*)d_in[9];
  const float* attF_w  = (const float*)d_in[10];
  const float* attF_b  = (const float*)d_in[11];
  const float* fuse1_w = (const float*)d_in[12];
  const float* fuse1_b = (const float*)d_in[13];
  const float* enc_Wih = (const float*)d_in[14];
  const float* enc_Whh = (const float*)d_in[15];
  const float* enc_bih = (const float*)d_in[16];
  const float* enc_bhh = (const float*)d_in[17];
  const float* enc2_Wih= (const float*)d_in[18];
  const float* enc2_Whh= (const float*)d_in[19];
  const float* enc2_bih= (const float*)d_in[20];
  const float* enc2_bhh= (const float*)d_in[21];
  const float* mlp1_w  = (const float*)d_in[22];
  const float* mlp1_b  = (const float*)d_in[23];
  const float* mlp2_w  = (const float*)d_in[24];
  const float* mlp2_b  = (const float*)d_in[25];

  float* ws = (float*)d_ws;
  size_t off = 0;
  float* g_h_node = ws + off; off += (size_t)B_SZ*8*64;
  float* g_c_node = ws + off; off += (size_t)B_SZ*8*64;
  float* g_h_tsa  = ws + off; off += (size_t)B_SZ*64;
  float* g_c_ts   = ws + off; off += (size_t)B_SZ*64;
  size_t state_fl = off;
  float* W4ts = ws + off; off += 12*20480;
  float* b4ts = ws + off; off += 12*256;
  float* W4nd = ws + off; off += (size_t)96*20480;
  float* b4nd = ws + off; off += 96*256;
  float* Qt   = ws + off; off += 4096;
  float* Vt   = ws + off; off += 4096;
  float* Ft   = ws + off; off += 8192;
  float* F1a  = ws + off; off += 4096;
  float* F1b  = ws + off; off += 4096;

  hipMemsetAsync(g_h_node, 0, state_fl*sizeof(float), stream);

  prep_w_kernel<<<(12*80*64+255)/256, 256, 0, stream>>>(enc_Wih, enc_Whh, emb_w, W4ts, 12);
  prep_w_kernel<<<(96*80*64+255)/256, 256, 0, stream>>>(enc2_Wih, enc2_Whh, emb_w, W4nd, 96);
  prep_b_kernel<<<(12*64+255)/256, 256, 0, stream>>>(enc_bih, enc_bhh, enc_Wih, emb_b, b4ts, 12);
  prep_b_kernel<<<(96*64+255)/256, 256, 0, stream>>>(enc2_bih, enc2_bhh, enc2_Wih, emb_b, b4nd, 96);
  prep_att_kernel<<<32, 256, 0, stream>>>(attQ_w, attV_w, attF_w, fuse1_w, Qt, Vt, Ft, F1a, F1b);

  StepPtrs P;
  P.ts = ts; P.gts = gts; P.W4ts = W4ts; P.b4ts = b4ts; P.W4nd = W4nd; P.b4nd = b4nd;
  P.Qt = Qt; P.Kw = attK_w; P.Vt = Vt; P.Ft = Ft; P.F1a = F1a; P.F1b = F1b;
  P.Qb = attQ_b; P.Vb = attV_b; P.Fb = attF_b; P.f1b = fuse1_b;
  P.h_node = g_h_node; P.c_node = g_c_node; P.h_tsa_g = g_h_tsa; P.c_ts = g_c_ts;

  for (int t = 0; t < T_SZ; t++)
    step_kernel<<<B_SZ/R_WG, NTHR, 0, stream>>>(P, t);

  final_kernel<<<B_SZ/64, 256, 0, stream>>>(g_h_tsa, mlp1_w, mlp1_b, mlp2_w, mlp2_b, (float*)d_out);
}

// Round 2
// 2925.661 us; speedup vs baseline: 1.2473x; 1.2473x over previous
//
#include <hip/hip_runtime.h>

#define T_SZ 12
#define R_WG 16
#define NTHR 256
#define NWG  512   // 8192 / R_WG

__device__ __forceinline__ float sigm(float x){ return 1.f/(1.f + __expf(-x)); }
__device__ __forceinline__ float tanh_f(float x){
  float e = __expf(-2.f*fabsf(x));
  float t = (1.f - e)/(1.f + e);
  return x < 0.f ? -t : t;
}

// a[ri*4+g] += sum_{c<4} x[row][k+c] * W[k+c][u][g]
__device__ __forceinline__ void gemm_k4(float a[16], const float4* wb, int kk, int u,
                                        const float* xbase, int xstride, int xoff, int rbase){
  float4 wv0 = wb[(kk+0)*64+u], wv1 = wb[(kk+1)*64+u];
  float4 wv2 = wb[(kk+2)*64+u], wv3 = wb[(kk+3)*64+u];
  #pragma unroll
  for (int ri=0; ri<4; ri++){
    float4 xv = *(const float4*)(xbase + (rbase+ri)*xstride + xoff);
    a[ri*4+0] += xv.x*wv0.x + xv.y*wv1.x + xv.z*wv2.x + xv.w*wv3.x;
    a[ri*4+1] += xv.x*wv0.y + xv.y*wv1.y + xv.z*wv2.y + xv.w*wv3.y;
    a[ri*4+2] += xv.x*wv0.z + xv.y*wv1.z + xv.z*wv2.z + xv.w*wv3.z;
    a[ri*4+3] += xv.x*wv0.w + xv.y*wv1.w + xv.z*wv2.w + xv.w*wv3.w;
  }
}

// Full K=80 LSTM: x = [xin(16) | h(64)], W global [80][u][4gates], bias global [u][4].
// Stages W in 4 quarters of 20 k-rows through wbuf (5120 floats) with register prefetch.
__device__ __forceinline__ void lstm_full(
    const float* __restrict__ Wg, const float* __restrict__ bg,
    const float* __restrict__ xg, int xgstride,
    const float* hbase, int hstride,
    float* cr, float* hdst, int hdststride,
    float* wbuf, float* xinb, float* b4b, int tid)
{
  const int u = tid & 63, rbase = (tid>>6)*4;
  const float4* wb4 = (const float4*)wbuf;
  float4* wbw = (float4*)wbuf;
  const float4* Wg4 = (const float4*)Wg;
  float a[16];
  #pragma unroll
  for (int i=0;i<16;i++) a[i]=0.f;

  // prefetch quarter 0 + x + b into registers (overlaps with prior phase's tail)
  float4 pv0=Wg4[tid], pv1=Wg4[tid+256], pv2=Wg4[tid+512], pv3=Wg4[tid+768], pv4=Wg4[tid+1024];
  const int xr = tid>>4, xm = tid&15;
  float xv = xg[xr*xgstride + xm];
  float bv = bg[tid];

  __syncthreads();                 // wbuf/xinb/b4b free (previous consumers done)
  wbw[tid]=pv0; wbw[tid+256]=pv1; wbw[tid+512]=pv2; wbw[tid+768]=pv3; wbw[tid+1024]=pv4;
  xinb[xr*16+xm] = xv;
  b4b[tid] = bv;
  __syncthreads();
  // prefetch quarter 1 while computing quarter 0
  pv0=Wg4[1280+tid]; pv1=Wg4[1280+tid+256]; pv2=Wg4[1280+tid+512]; pv3=Wg4[1280+tid+768]; pv4=Wg4[1280+tid+1024];

  gemm_k4(a, wb4, 0,  u, xinb, 16, 0,  rbase);
  gemm_k4(a, wb4, 4,  u, xinb, 16, 4,  rbase);
  gemm_k4(a, wb4, 8,  u, xinb, 16, 8,  rbase);
  gemm_k4(a, wb4, 12, u, xinb, 16, 12, rbase);
  gemm_k4(a, wb4, 16, u, hbase, hstride, 0, rbase);

  #pragma unroll 1
  for (int q=1;q<4;q++){
    __syncthreads();
    wbw[tid]=pv0; wbw[tid+256]=pv1; wbw[tid+512]=pv2; wbw[tid+768]=pv3; wbw[tid+1024]=pv4;
    __syncthreads();
    if (q<3){
      const float4* s = Wg4 + (q+1)*1280;
      pv0=s[tid]; pv1=s[tid+256]; pv2=s[tid+512]; pv3=s[tid+768]; pv4=s[tid+1024];
    }
    int xo = q*20-16;
    gemm_k4(a, wb4, 0,  u, hbase, hstride, xo+0,  rbase);
    gemm_k4(a, wb4, 4,  u, hbase, hstride, xo+4,  rbase);
    gemm_k4(a, wb4, 8,  u, hbase, hstride, xo+8,  rbase);
    gemm_k4(a, wb4, 12, u, hbase, hstride, xo+12, rbase);
    gemm_k4(a, wb4, 16, u, hbase, hstride, xo+16, rbase);
  }
  __syncthreads();    // all h reads done before hdst write (hdst may alias hbase)
  #pragma unroll
  for (int ri=0;ri<4;ri++){
    float iv = sigm(a[ri*4+0] + b4b[u*4+0]);
    float fv = sigm(a[ri*4+1] + b4b[u*4+1]);
    float gv = tanh_f(a[ri*4+2] + b4b[u*4+2]);
    float ov = sigm(a[ri*4+3] + b4b[u*4+3]);
    float c2 = fv*cr[ri] + iv*gv;
    cr[ri] = c2;
    hdst[(rbase+ri)*hdststride + u] = ov*tanh_f(c2);
  }
}

// out[row][u] = act( acc + bias[u] (+ out[row][u]) ), K=64, w in LDS [k][64]
__device__ __forceinline__ void sgemm(float* out, int ostride, const float* x, int xstride,
                                      const float* w, const float* bias_g,
                                      bool add, bool relu, int tid){
  const int u = tid&63, rbase = (tid>>6)*4;
  float bv = bias_g ? bias_g[u] : 0.f;
  float acc0=0.f, acc1=0.f, acc2=0.f, acc3=0.f;
  #pragma unroll 4
  for (int k=0;k<64;k+=4){
    float w0=w[k*64+u], w1=w[(k+1)*64+u], w2=w[(k+2)*64+u], w3=w[(k+3)*64+u];
    float4 x0=*(const float4*)(x+(rbase+0)*xstride+k);
    float4 x1=*(const float4*)(x+(rbase+1)*xstride+k);
    float4 x2=*(const float4*)(x+(rbase+2)*xstride+k);
    float4 x3=*(const float4*)(x+(rbase+3)*xstride+k);
    acc0 += x0.x*w0 + x0.y*w1 + x0.z*w2 + x0.w*w3;
    acc1 += x1.x*w0 + x1.y*w1 + x1.z*w2 + x1.w*w3;
    acc2 += x2.x*w0 + x2.y*w1 + x2.z*w2 + x2.w*w3;
    acc3 += x3.x*w0 + x3.y*w1 + x3.z*w2 + x3.w*w3;
  }
  float accs[4]={acc0,acc1,acc2,acc3};
  #pragma unroll
  for (int ri=0;ri<4;ri++){
    int idx=(rbase+ri)*ostride+u;
    float v=accs[ri]+bv;
    if (add)  v += out[idx];
    if (relu) v = fmaxf(v,0.f);
    out[idx]=v;
  }
}

__device__ __forceinline__ void stage4k(float* wbuf, const float* src, int tid){
  float4* d=(float4*)wbuf; const float4* s=(const float4*)src;
  #pragma unroll
  for (int j=0;j<4;j++) d[tid+j*256]=s[tid+j*256];
}

struct Ptrs {
  const float* ts; const float* gts;
  const float* W4ts; const float* b4ts;
  const float* W4nd; const float* b4nd;
  const float* Qt; const float* Kw; const float* Vt; const float* Ft;
  const float* F1a; const float* F1b;
  const float* Qb; const float* Vb; const float* Fb; const float* f1b;
  const float* m1w; const float* m1b; const float* m2w; const float* m2b;
  float* out;
};

__global__ __launch_bounds__(NTHR, 2) void fused_kernel(Ptrs P){
  __shared__ __align__(16) float h_node[R_WG*8*64];  // 32 KB
  __shared__ __align__(16) float h_tsa [R_WG*64];
  __shared__ __align__(16) float h_ts  [R_WG*64];
  __shared__ __align__(16) float tmpA  [R_WG*64];
  __shared__ __align__(16) float tmpB  [R_WG*64];
  __shared__ __align__(16) float tsb   [R_WG*16];
  __shared__ __align__(16) float wbuf  [5120];       // 20 KB weight stage
  __shared__ __align__(16) float b4b   [256];
  __shared__ float pbuf[128];

  const int tid = threadIdx.x;
  const int r0  = blockIdx.x * R_WG;
  const int u = tid&63, rbase = (tid>>6)*4;

  float c_ts[4] = {0.f,0.f,0.f,0.f};
  float c_nd[32];
  #pragma unroll
  for (int i=0;i<32;i++) c_nd[i]=0.f;

  for (int i=tid;i<R_WG*512;i+=NTHR) h_node[i]=0.f;
  for (int i=tid;i<R_WG*64;i+=NTHR)  h_tsa[i]=0.f;
  // visibility guaranteed by the barriers inside the first lstm_full

  for (int t=0;t<T_SZ;t++){
    // ---- A: ts LSTM (x=[ts_t | h_tsa]) ----
    lstm_full(P.W4ts + t*20480, P.b4ts + t*256,
              P.ts + (size_t)r0*192 + t*16, 192,
              h_tsa, 64, c_ts, h_ts, 64,
              wbuf, tsb, b4b, tid);

    // ---- B: 8 node LSTMs (x=[gts_t | h_node[n]]) ----
    #pragma unroll
    for (int n=0;n<8;n++){
      lstm_full(P.W4nd + (size_t)(n*T_SZ+t)*20480, P.b4nd + (n*T_SZ+t)*256,
                P.gts + ((size_t)r0*8+n)*192 + t*16, 1536,
                h_node + n*64, 512, c_nd + n*4, h_node + n*64, 512,
                wbuf, tsb, b4b, tid);
    }

    // ---- C: attention ----
    __syncthreads();
    stage4k(wbuf, P.Qt, tid);
    __syncthreads();
    sgemm(tmpA, 64, h_ts, 64, wbuf, P.Qb, false, false, tid);   // q
    __syncthreads();
    stage4k(wbuf, P.Kw, tid);
    __syncthreads();
    sgemm(tmpB, 64, tmpA, 64, wbuf, nullptr, false, false, tid); // qk = q @ Kw
    __syncthreads();
    if (tid < 128){
      int r=tid>>3, n=tid&7, lane=tid&63;
      float s=0.f;
      for (int c0=0;c0<64;c0++){
        int c=(c0+lane)&63;
        s += h_node[(r*8+n)*64+c]*tmpB[r*64+c];
      }
      s *= 0.125f;
      float mx=s;
      mx=fmaxf(mx,__shfl_xor(mx,1,8));
      mx=fmaxf(mx,__shfl_xor(mx,2,8));
      mx=fmaxf(mx,__shfl_xor(mx,4,8));
      float e=__expf(s-mx);
      float sm=e;
      sm+=__shfl_xor(sm,1,8); sm+=__shfl_xor(sm,2,8); sm+=__shfl_xor(sm,4,8);
      pbuf[tid]=e/sm;
    }
    __syncthreads();
    { // hbar = sum_n p_n h_node[n] -> tmpA
      #pragma unroll
      for (int ri=0;ri<4;ri++){
        int r=rbase+ri;
        float sacc=0.f;
        #pragma unroll
        for (int n=0;n<8;n++) sacc += pbuf[r*8+n]*h_node[(r*8+n)*64+u];
        tmpA[r*64+u]=sacc;
      }
    }
    __syncthreads();
    stage4k(wbuf, P.Vt, tid);
    __syncthreads();
    sgemm(tmpB, 64, tmpA, 64, wbuf, P.Vb, false, false, tid);    // ctx
    __syncthreads();
    stage4k(wbuf, P.Ft, tid);                                    // FtA (ctx part)
    __syncthreads();
    sgemm(h_tsa, 64, tmpB, 64, wbuf, P.Fb, false, false, tid);
    __syncthreads();
    stage4k(wbuf, P.Ft+4096, tid);                               // FtB (query part)
    __syncthreads();
    sgemm(h_tsa, 64, h_ts, 64, wbuf, nullptr, true, true, tid);  // += , relu
    __syncthreads();
    stage4k(wbuf, P.F1b, tid);
    __syncthreads();
    sgemm(tmpA, 64, h_ts, 64, wbuf, P.f1b, false, false, tid);   // f_ts
    __syncthreads();
    stage4k(wbuf, P.F1a, tid);
    __syncthreads();
    { // fused fusion gemm over all 8 nodes, results in regs, then write back
      float fa[32];
      #pragma unroll
      for (int i=0;i<32;i++) fa[i]=0.f;
      #pragma unroll 4
      for (int k=0;k<64;k+=4){
        float w0=wbuf[k*64+u], w1=wbuf[(k+1)*64+u], w2=wbuf[(k+2)*64+u], w3=wbuf[(k+3)*64+u];
        #pragma unroll
        for (int n=0;n<8;n++){
          #pragma unroll
          for (int ri=0;ri<4;ri++){
            float4 xv=*(const float4*)(h_node+((rbase+ri)*8+n)*64+k);
            fa[n*4+ri]+=xv.x*w0+xv.y*w1+xv.z*w2+xv.w*w3;
          }
        }
      }
      __syncthreads();   // all h_node reads done before overwrite
      #pragma unroll
      for (int n=0;n<8;n++){
        #pragma unroll
        for (int ri=0;ri<4;ri++){
          float v=fa[n*4+ri]+tmpA[(rbase+ri)*64+u];
          h_node[((rbase+ri)*8+n)*64+u]=fmaxf(v,0.f);
        }
      }
    }
    __syncthreads();
  }

  // ---- final MLP: out = relu(h_tsa@m1.T + b1) @ m2.T + b2 ----
  {
    float4* d=(float4*)wbuf; const float4* s=(const float4*)P.m1w;
    #pragma unroll
    for (int j=0;j<2;j++) d[tid+j*256]=s[tid+j*256];
    if (tid<32) b4b[tid]=P.m1b[tid];
    else if (tid<64) b4b[tid]=P.m2w[tid-32];
  }
  __syncthreads();
  {
    int r=tid>>4, i2=tid&15;
    #pragma unroll
    for (int jj=0;jj<2;jj++){
      int i=i2*2+jj;
      float hsum=b4b[i];
      #pragma unroll 4
      for (int k=0;k<64;k+=4){
        float4 xv=*(const float4*)(h_tsa+r*64+k);
        hsum += xv.x*wbuf[i*64+k] + xv.y*wbuf[i*64+k+1] + xv.z*wbuf[i*64+k+2] + xv.w*wbuf[i*64+k+3];
      }
      tmpA[r*32+i]=fmaxf(hsum,0.f);
    }
  }
  __syncthreads();
  if (tid < R_WG){
    float sacc=P.m2b[0];
    for (int i=0;i<32;i++) sacc += tmpA[tid*32+i]*b4b[32+i];
    P.out[r0+tid]=sacc;
  }
}

// ---- prep: fold embedding into Wih, layout [l][k][u][4gates]; biases [l][u][4] ----
__global__ void prep_w_kernel(const float* Wih, const float* Whh, const float* emb_w,
                              float* dst, int L){
  int idx = blockIdx.x*256 + threadIdx.x;
  int total = L*80*64;
  if (idx >= total) return;
  int l = idx / (80*64);
  int rem = idx % (80*64);
  int k = rem / 64;
  int u = rem & 63;
  float v[4];
  if (k < 16){
    #pragma unroll
    for (int g=0;g<4;g++){
      int j = g*64+u;
      float s = 0.f;
      for (int i=0;i<32;i++) s += Wih[((size_t)l*256+j)*32+i]*emb_w[i*16+k];
      v[g]=s;
    }
  } else {
    #pragma unroll
    for (int g=0;g<4;g++) v[g]=Whh[((size_t)l*256+g*64+u)*64+(k-16)];
  }
  float* d = dst + (size_t)l*20480 + k*256 + u*4;
  d[0]=v[0]; d[1]=v[1]; d[2]=v[2]; d[3]=v[3];
}

__global__ void prep_b_kernel(const float* bih, const float* bhh, const float* Wih,
                              const float* emb_b, float* dst, int L){
  int idx = blockIdx.x*256 + threadIdx.x;
  if (idx >= L*64) return;
  int l = idx/64, u = idx&63;
  #pragma unroll
  for (int g=0;g<4;g++){
    int j=g*64+u;
    float s = bih[l*256+j] + bhh[l*256+j];
    for (int i=0;i<32;i++) s += Wih[((size_t)l*256+j)*32+i]*emb_b[i];
    dst[l*256 + u*4 + g] = s;
  }
}

__global__ void prep_att_kernel(const float* Qw, const float* Vw, const float* Fw, const float* f1w,
                                float* Qt, float* Vt, float* Ft, float* F1a, float* F1b){
  int idx = blockIdx.x*256 + threadIdx.x;
  if (idx < 4096){
    int c = idx >> 6, u = idx & 63;
    Qt[c*64+u]  = Qw[u*64+c];
    Vt[c*64+u]  = Vw[u*64+c];
    F1a[c*64+u] = f1w[u*128 + c];
    F1b[c*64+u] = f1w[u*128 + 64 + c];
  }
  if (idx < 8192){
    int m = idx >> 6, j = idx & 63;
    Ft[m*64+j] = Fw[j*128 + m];
  }
}

extern "C" void kernel_launch(void* const* d_in, const int* in_sizes, int n_in,
                              void* d_out, int out_size, void* d_ws, size_t ws_size,
                              hipStream_t stream){
  const float* ts      = (const float*)d_in[0];
  const float* gts     = (const float*)d_in[1];
  const float* emb_w   = (const float*)d_in[2];
  const float* emb_b   = (const float*)d_in[3];
  const float* attQ_w  = (const float*)d_in[4];
  const float* attQ_b  = (const float*)d_in[5];
  const float* attK_w  = (const float*)d_in[6];
  // d_in[7] = attK_b : constant shift under softmax, unused
  const float* attV_w  = (const float*)d_in[8];
  const float* attV_b  = (const float*)d_in[9];
  const float* attF_w  = (const float*)d_in[10];
  const float* attF_b  = (const float*)d_in[11];
  const float* fuse1_w = (const float*)d_in[12];
  const float* fuse1_b = (const float*)d_in[13];
  const float* enc_Wih = (const float*)d_in[14];
  const float* enc_Whh = (const float*)d_in[15];
  const float* enc_bih = (const float*)d_in[16];
  const float* enc_bhh = (const float*)d_in[17];
  const float* enc2_Wih= (const float*)d_in[18];
  const float* enc2_Whh= (const float*)d_in[19];
  const float* enc2_bih= (const float*)d_in[20];
  const float* enc2_bhh= (const float*)d_in[21];
  const float* mlp1_w  = (const float*)d_in[22];
  const float* mlp1_b  = (const float*)d_in[23];
  const float* mlp2_w  = (const float*)d_in[24];
  const float* mlp2_b  = (const float*)d_in[25];

  float* ws = (float*)d_ws;
  size_t off = 0;
  float* W4ts = ws + off; off += 12*20480;
  float* b4ts = ws + off; off += 12*256;
  float* W4nd = ws + off; off += (size_t)96*20480;
  float* b4nd = ws + off; off += 96*256;
  float* Qt   = ws + off; off += 4096;
  float* Vt   = ws + off; off += 4096;
  float* Ft   = ws + off; off += 8192;
  float* F1a  = ws + off; off += 4096;
  float* F1b  = ws + off; off += 4096;

  prep_w_kernel<<<(12*80*64+255)/256, 256, 0, stream>>>(enc_Wih, enc_Whh, emb_w, W4ts, 12);
  prep_w_kernel<<<(96*80*64+255)/256, 256, 0, stream>>>(enc2_Wih, enc2_Whh, emb_w, W4nd, 96);
  prep_b_kernel<<<(12*64+255)/256, 256, 0, stream>>>(enc_bih, enc_bhh, enc_Wih, emb_b, b4ts, 12);
  prep_b_kernel<<<(96*64+255)/256, 256, 0, stream>>>(enc2_bih, enc2_bhh, enc2_Wih, emb_b, b4nd, 96);
  prep_att_kernel<<<32, 256, 0, stream>>>(attQ_w, attV_w, attF_w, fuse1_w, Qt, Vt, Ft, F1a, F1b);

  Ptrs P;
  P.ts=ts; P.gts=gts; P.W4ts=W4ts; P.b4ts=b4ts; P.W4nd=W4nd; P.b4nd=b4nd;
  P.Qt=Qt; P.Kw=attK_w; P.Vt=Vt; P.Ft=Ft; P.F1a=F1a; P.F1b=F1b;
  P.Qb=attQ_b; P.Vb=attV_b; P.Fb=attF_b; P.f1b=fuse1_b;
  P.m1w=mlp1_w; P.m1b=mlp1_b; P.m2w=mlp2_w; P.m2b=mlp2_b;
  P.out=(float*)d_out;

  fused_kernel<<<NWG, NTHR, 0, stream>>>(P);
}

// Round 3
// 2439.238 us; speedup vs baseline: 1.4961x; 1.1994x over previous
//
#include <hip/hip_runtime.h>

#define T_SZ 12
#define R_WG 16
#define NTHR 256
#define NWG  512   // 8192 / R_WG

typedef const __attribute__((address_space(1))) void* gas1_t;
typedef __attribute__((address_space(3))) void* las3_t;

__device__ __forceinline__ void gload16(const void* g, void* l){
  __builtin_amdgcn_global_load_lds((gas1_t)g, (las3_t)l, 16, 0, 0);
}

__device__ __forceinline__ float sigm(float x){ return 1.f/(1.f + __expf(-x)); }
__device__ __forceinline__ float tanh_f(float x){
  float e = __expf(-2.f*fabsf(x));
  float t = (1.f - e)/(1.f + e);
  return x < 0.f ? -t : t;
}

// stage one 16-k-row weight chunk (1024 float4) into LDS: linear, lane x 16B
__device__ __forceinline__ void issue_chunk(const float4* gsrc, float* lbuf, int tid){
  const int wv = tid>>6, ln = tid&63;
  #pragma unroll
  for (int j=0;j<4;j++){
    int idx = j*256 + wv*64;               // wave-uniform float4 index
    gload16(gsrc + idx + ln, (float4*)lbuf + idx);
  }
}

// stage 16 rows x 16 floats of x into tsb (one wave: 64 lanes = 64 float4)
__device__ __forceinline__ void issue_xin(const float* gsrc, int rowstride_f4, float* tsb, int ln){
  int r = ln>>2, q = ln&3;
  gload16((const float4*)gsrc + (size_t)r*rowstride_f4 + q, tsb);
}

// a[ri*4+g] += sum_{c<4} x[row][k+c] * W[k+c][u][g]   (W chunk in LDS, x broadcast)
__device__ __forceinline__ void gemm_k4(float a[16], const float4* wb, int kk, int u,
                                        const float* xbase, int xstride, int xoff, int rbase){
  float4 wv0 = wb[(kk+0)*64+u], wv1 = wb[(kk+1)*64+u];
  float4 wv2 = wb[(kk+2)*64+u], wv3 = wb[(kk+3)*64+u];
  #pragma unroll
  for (int ri=0; ri<4; ri++){
    float4 xv = *(const float4*)(xbase + (rbase+ri)*xstride + xoff);
    a[ri*4+0] += xv.x*wv0.x + xv.y*wv1.x + xv.z*wv2.x + xv.w*wv3.x;
    a[ri*4+1] += xv.x*wv0.y + xv.y*wv1.y + xv.z*wv2.y + xv.w*wv3.y;
    a[ri*4+2] += xv.x*wv0.z + xv.y*wv1.z + xv.z*wv2.z + xv.w*wv3.z;
    a[ri*4+3] += xv.x*wv0.w + xv.y*wv1.w + xv.z*wv2.w + xv.w*wv3.w;
  }
}

// out[r][u] = act( sum_k x[r][k] * Wg[u][k] + bias[u] (+out) ), weights row-major, direct global
__device__ __forceinline__ void sgemm_row(float* out, int ostride, const float* x, int xstride,
                                          const float* Wg, int wstride, const float* bias,
                                          bool add, bool relu, int u, int rbase){
  const float* wrow = Wg + (size_t)u*wstride;
  float acc[4] = {0.f,0.f,0.f,0.f};
  #pragma unroll
  for (int k=0;k<64;k+=4){
    float4 wv = *(const float4*)(wrow + k);
    #pragma unroll
    for (int ri=0;ri<4;ri++){
      float4 xv = *(const float4*)(x + (rbase+ri)*xstride + k);
      acc[ri] += xv.x*wv.x + xv.y*wv.y + xv.z*wv.z + xv.w*wv.w;
    }
  }
  float b = bias ? bias[u] : 0.f;
  #pragma unroll
  for (int ri=0;ri<4;ri++){
    int idx = (rbase+ri)*ostride + u;
    float v = acc[ri] + b;
    if (add)  v += out[idx];
    if (relu) v = fmaxf(v, 0.f);
    out[idx] = v;
  }
}

// out[r][u] = sum_k x[r][k] * Wg[k][u]   (column access, scalar coalesced global loads)
__device__ __forceinline__ void sgemm_col(float* out, const float* x, const float* Wg,
                                          int u, int rbase){
  float acc[4] = {0.f,0.f,0.f,0.f};
  #pragma unroll
  for (int k=0;k<64;k+=4){
    float w0=Wg[(k+0)*64+u], w1=Wg[(k+1)*64+u], w2=Wg[(k+2)*64+u], w3=Wg[(k+3)*64+u];
    #pragma unroll
    for (int ri=0;ri<4;ri++){
      float4 xv = *(const float4*)(x + (rbase+ri)*64 + k);
      acc[ri] += xv.x*w0 + xv.y*w1 + xv.z*w2 + xv.w*w3;
    }
  }
  #pragma unroll
  for (int ri=0;ri<4;ri++) out[(rbase+ri)*64+u] = acc[ri];
}

struct Ptrs {
  const float* ts; const float* gts;
  const float* W4ts; const float* b4ts;
  const float* W4nd; const float* b4nd;
  const float* Qw; const float* Qb; const float* Kw;
  const float* Vw; const float* Vb; const float* Fw; const float* Fb;
  const float* f1w; const float* f1b;
  const float* m1w; const float* m1b; const float* m2w; const float* m2b;
  float* cg; float* out;
};

__global__ __launch_bounds__(NTHR, 2) void fused_kernel(Ptrs P){
  __shared__ __align__(16) float bufA[4096];    // 16 KB chunk buffer / attn tmps
  __shared__ __align__(16) float bufB[4096];    // 16 KB chunk buffer / final hid
  __shared__ __align__(16) float h_node[8192];  // 32 KB: [r][n][64]
  __shared__ __align__(16) float h_ts [1024];
  __shared__ __align__(16) float h_tsa[1024];
  __shared__ __align__(16) float tsb  [256];    // [16][16] x-input stage
  __shared__ float pbuf[128];

  const int tid = threadIdx.x;
  const int r0  = blockIdx.x * R_WG;
  const int u = tid&63, wv = tid>>6, ln = tid&63;
  const int rbase = wv*4;
  float* tmpA = bufA;            // aliases: live only during attention/fusion
  float* tmpB = bufA + 1024;

  float c_ts[4] = {0.f,0.f,0.f,0.f};

  for (int i=tid;i<8192;i+=NTHR) h_node[i]=0.f;
  for (int i=tid;i<1024;i+=NTHR) h_tsa[i]=0.f;

  for (int t=0;t<T_SZ;t++){
    __syncthreads();   // bufA free (fusion / init done)
    // ---- prologue: stage A-lstm chunk0 + its x ----
    issue_chunk((const float4*)P.W4ts + (size_t)t*5120, bufA, tid);
    if (wv==0) issue_xin(P.ts + (size_t)r0*192 + t*16, 48, tsb, ln);
    __syncthreads();   // barrier drains vmcnt -> chunk0 + tsb ready
    int p = 0;

    // ---- 9 LSTMs: l=0 is the ts-LSTM, l=1..8 are nodes 0..7 ----
    for (int l=0;l<9;l++){
      const float4* Wcur = (l==0) ? (const float4*)P.W4ts + (size_t)t*5120
                                  : (const float4*)P.W4nd + (size_t)((l-1)*T_SZ+t)*5120;
      const float* hb   = (l==0) ? h_tsa : h_node + (l-1)*64;
      const int hstride = (l==0) ? 64 : 512;
      float a[16];
      #pragma unroll
      for (int i=0;i<16;i++) a[i]=0.f;

      for (int q=0;q<5;q++){
        float* bufc = p ? bufB : bufA;
        float* bufn = p ? bufA : bufB;
        if (q<4){
          issue_chunk(Wcur + (q+1)*1024, bufn, tid);
        } else if (l<8){   // chain: next LSTM's chunk0 + x
          issue_chunk((const float4*)P.W4nd + (size_t)(l*T_SZ+t)*5120, bufn, tid);
          if (wv==0) issue_xin(P.gts + ((size_t)r0*8 + l)*192 + t*16, 384, tsb, ln);
        }
        const float* xb = (q==0) ? tsb : hb;
        const int xs    = (q==0) ? 16  : hstride;
        const int xo    = (q==0) ? 0   : (q-1)*16;
        const float4* wb4 = (const float4*)bufc;
        #pragma unroll
        for (int kk=0;kk<16;kk+=4)
          gemm_k4(a, wb4, kk, u, xb, xs, xo+kk, rbase);
        __syncthreads();   // drains just-issued loads; bufc free for reuse
        p ^= 1;
      }

      // ---- nonlinearity ----
      const float* bias = (l==0) ? P.b4ts + t*256 : P.b4nd + ((l-1)*T_SZ+t)*256;
      float4 bv = *(const float4*)(bias + u*4);
      #pragma unroll
      for (int ri=0;ri<4;ri++){
        float iv = sigm(a[ri*4+0]+bv.x);
        float fv = sigm(a[ri*4+1]+bv.y);
        float gv = tanh_f(a[ri*4+2]+bv.z);
        float ov = sigm(a[ri*4+3]+bv.w);
        float cold;
        if (l==0) cold = c_ts[ri];
        else      cold = (t==0) ? 0.f
                       : P.cg[((size_t)(l-1)*8192 + r0+rbase+ri)*64 + u];
        float c2 = fv*cold + iv*gv;
        float hv = ov*tanh_f(c2);
        if (l==0){ c_ts[ri]=c2; h_ts[(rbase+ri)*64+u]=hv; }
        else { P.cg[((size_t)(l-1)*8192 + r0+rbase+ri)*64 + u] = c2;
               h_node[((rbase+ri)*8+(l-1))*64+u] = hv; }
      }
    }
    __syncthreads();   // all h writes visible

    // ---- attention (weights direct from global, L2-resident) ----
    sgemm_row(tmpA, 64, h_ts, 64, P.Qw, 64, P.Qb, false, false, u, rbase);   // q
    __syncthreads();
    sgemm_col(tmpB, tmpA, P.Kw, u, rbase);                                   // qk = q @ Kw
    __syncthreads();
    if (tid < 128){   // scores + softmax over n
      int r=tid>>3, n=tid&7, lane=tid&63;
      float s=0.f;
      for (int c0=0;c0<64;c0++){
        int c=(c0+lane)&63;
        s += h_node[(r*8+n)*64+c]*tmpB[r*64+c];
      }
      s *= 0.125f;
      float mx=s;
      mx=fmaxf(mx,__shfl_xor(mx,1,8));
      mx=fmaxf(mx,__shfl_xor(mx,2,8));
      mx=fmaxf(mx,__shfl_xor(mx,4,8));
      float e=__expf(s-mx);
      float sm=e;
      sm+=__shfl_xor(sm,1,8); sm+=__shfl_xor(sm,2,8); sm+=__shfl_xor(sm,4,8);
      pbuf[tid]=e/sm;
    }
    __syncthreads();
    { // hbar = sum_n p_n h_node[n] -> tmpA (q dead)
      #pragma unroll
      for (int ri=0;ri<4;ri++){
        int r=rbase+ri;
        float sacc=0.f;
        #pragma unroll
        for (int n=0;n<8;n++) sacc += pbuf[r*8+n]*h_node[(r*8+n)*64+u];
        tmpA[r*64+u]=sacc;
      }
    }
    __syncthreads();
    sgemm_row(tmpB, 64, tmpA, 64, P.Vw, 64, P.Vb, false, false, u, rbase);   // ctx
    __syncthreads();
    sgemm_row(h_tsa, 64, tmpB, 64, P.Fw,    128, P.Fb, false, false, u, rbase); // ctx part
    sgemm_row(h_tsa, 64, h_ts, 64, P.Fw+64, 128, nullptr, true, true, u, rbase); // + query, relu
    __syncthreads();   // tmpA readers (ctx) done before overwrite
    sgemm_row(tmpA, 64, h_ts, 64, P.f1w+64, 128, P.f1b, false, false, u, rbase); // f_ts

    // ---- fusion over all 8 nodes ----
    {
      const float* wrow = P.f1w + (size_t)u*128;   // cols 0..63
      float fa[32];
      #pragma unroll
      for (int i=0;i<32;i++) fa[i]=0.f;
      #pragma unroll 4
      for (int k=0;k<64;k+=4){
        float4 wvv = *(const float4*)(wrow + k);
        #pragma unroll
        for (int ri=0;ri<4;ri++){
          #pragma unroll
          for (int n=0;n<8;n++){
            float4 xv = *(const float4*)(h_node + ((rbase+ri)*8+n)*64 + k);
            fa[ri*8+n] += xv.x*wvv.x + xv.y*wvv.y + xv.z*wvv.z + xv.w*wvv.w;
          }
        }
      }
      __syncthreads();   // all h_node reads done before overwrite
      #pragma unroll
      for (int ri=0;ri<4;ri++){
        #pragma unroll
        for (int n=0;n<8;n++){
          float v = fa[ri*8+n] + tmpA[(rbase+ri)*64+u];   // own elements (written by this thread)
          h_node[((rbase+ri)*8+n)*64+u] = fmaxf(v,0.f);
        }
      }
    }
  }
  __syncthreads();

  // ---- final MLP: out = relu(h_tsa@m1.T + b1) @ m2.T + b2 ----
  {
    float* hidb = bufB;          // 16 rows x 32
    int r = tid>>4, i2 = tid&15;
    #pragma unroll
    for (int jj=0;jj<2;jj++){
      int i = i2 + jj*16;
      float hsum = P.m1b[i];
      #pragma unroll
      for (int k=0;k<64;k+=4){
        float4 wvv = *(const float4*)(P.m1w + (size_t)i*64 + k);
        float4 xv  = *(const float4*)(h_tsa + r*64 + k);
        hsum += xv.x*wvv.x + xv.y*wvv.y + xv.z*wvv.z + xv.w*wvv.w;
      }
      hidb[r*32+i] = fmaxf(hsum, 0.f);
    }
    __syncthreads();
    if (tid < R_WG){
      float s = P.m2b[0];
      for (int i=0;i<32;i++) s += hidb[tid*32+i]*P.m2w[i];
      P.out[r0+tid] = s;
    }
  }
}

// ---- prep: fold embedding into Wih; layout [l][k][u][4gates], biases [l][u][4] ----
__global__ void prep_w_kernel(const float* Wih, const float* Whh, const float* emb_w,
                              float* dst, int L){
  int idx = blockIdx.x*256 + threadIdx.x;
  int total = L*80*64;
  if (idx >= total) return;
  int l = idx / (80*64);
  int rem = idx % (80*64);
  int k = rem / 64;
  int u = rem & 63;
  float v[4];
  if (k < 16){
    #pragma unroll
    for (int g=0;g<4;g++){
      int j = g*64+u;
      float s = 0.f;
      for (int i=0;i<32;i++) s += Wih[((size_t)l*256+j)*32+i]*emb_w[i*16+k];
      v[g]=s;
    }
  } else {
    #pragma unroll
    for (int g=0;g<4;g++) v[g]=Whh[((size_t)l*256+g*64+u)*64+(k-16)];
  }
  float* d = dst + (size_t)l*20480 + k*256 + u*4;
  d[0]=v[0]; d[1]=v[1]; d[2]=v[2]; d[3]=v[3];
}

__global__ void prep_b_kernel(const float* bih, const float* bhh, const float* Wih,
                              const float* emb_b, float* dst, int L){
  int idx = blockIdx.x*256 + threadIdx.x;
  if (idx >= L*64) return;
  int l = idx/64, u = idx&63;
  #pragma unroll
  for (int g=0;g<4;g++){
    int j=g*64+u;
    float s = bih[l*256+j] + bhh[l*256+j];
    for (int i=0;i<32;i++) s += Wih[((size_t)l*256+j)*32+i]*emb_b[i];
    dst[l*256 + u*4 + g] = s;
  }
}

extern "C" void kernel_launch(void* const* d_in, const int* in_sizes, int n_in,
                              void* d_out, int out_size, void* d_ws, size_t ws_size,
                              hipStream_t stream){
  const float* ts      = (const float*)d_in[0];
  const float* gts     = (const float*)d_in[1];
  const float* emb_w   = (const float*)d_in[2];
  const float* emb_b   = (const float*)d_in[3];
  const float* attQ_w  = (const float*)d_in[4];
  const float* attQ_b  = (const float*)d_in[5];
  const float* attK_w  = (const float*)d_in[6];
  // d_in[7] = attK_b : constant shift under softmax, unused
  const float* attV_w  = (const float*)d_in[8];
  const float* attV_b  = (const float*)d_in[9];
  const float* attF_w  = (const float*)d_in[10];
  const float* attF_b  = (const float*)d_in[11];
  const float* fuse1_w = (const float*)d_in[12];
  const float* fuse1_b = (const float*)d_in[13];
  const float* enc_Wih = (const float*)d_in[14];
  const float* enc_Whh = (const float*)d_in[15];
  const float* enc_bih = (const float*)d_in[16];
  const float* enc_bhh = (const float*)d_in[17];
  const float* enc2_Wih= (const float*)d_in[18];
  const float* enc2_Whh= (const float*)d_in[19];
  const float* enc2_bih= (const float*)d_in[20];
  const float* enc2_bhh= (const float*)d_in[21];
  const float* mlp1_w  = (const float*)d_in[22];
  const float* mlp1_b  = (const float*)d_in[23];
  const float* mlp2_w  = (const float*)d_in[24];
  const float* mlp2_b  = (const float*)d_in[25];

  float* ws = (float*)d_ws;
  size_t off = 0;
  float* W4ts = ws + off; off += 12*20480;
  float* b4ts = ws + off; off += 12*256;
  float* W4nd = ws + off; off += (size_t)96*20480;
  float* b4nd = ws + off; off += 96*256;
  float* cg   = ws + off; off += (size_t)8*8192*64;

  prep_w_kernel<<<(12*80*64+255)/256, 256, 0, stream>>>(enc_Wih, enc_Whh, emb_w, W4ts, 12);
  prep_w_kernel<<<(96*80*64+255)/256, 256, 0, stream>>>(enc2_Wih, enc2_Whh, emb_w, W4nd, 96);
  prep_b_kernel<<<(12*64+255)/256, 256, 0, stream>>>(enc_bih, enc_bhh, enc_Wih, emb_b, b4ts, 12);
  prep_b_kernel<<<(96*64+255)/256, 256, 0, stream>>>(enc2_bih, enc2_bhh, enc2_Wih, emb_b, b4nd, 96);

  Ptrs P;
  P.ts=ts; P.gts=gts; P.W4ts=W4ts; P.b4ts=b4ts; P.W4nd=W4nd; P.b4nd=b4nd;
  P.Qw=attQ_w; P.Qb=attQ_b; P.Kw=attK_w;
  P.Vw=attV_w; P.Vb=attV_b; P.Fw=attF_w; P.Fb=attF_b;
  P.f1w=fuse1_w; P.f1b=fuse1_b;
  P.m1w=mlp1_w; P.m1b=mlp1_b; P.m2w=mlp2_w; P.m2b=mlp2_b;
  P.cg=cg; P.out=(float*)d_out;

  fused_kernel<<<NWG, NTHR, 0, stream>>>(P);
}